// Round 4
// baseline (269.709 us; speedup 1.0000x reference)
//
#include <hip/hip_runtime.h>
#include <hip/hip_bf16.h>
#include <math.h>

// Problem constants
#define Bn 8
#define Sn 4096
#define Dn 512
#define MODES 16
#define ANGF 0.0015339807878856412f  // 2*pi/4096

// ws layout (floats):
#define PART_OFF 0               //  8,388,608  fp32 [B*64][16][512] float2
#define Y_OFF 8388608            //  + 131,072  fp32 [B][16][512] float2
#define WTF_OFF 8519680          //  + 786,432  fp32 [3][512 d][512 o]
#define Z_OFF 9306112            //  + 393,216  fp32 [B][3 t][16][512] float2

// ---------------------------------------------------------------------------
// K1: fused (a) conv_w transpose, (b) LayerNorm-stats, (c) radix-4 16-mode
// DFT projection. 512 threads/block for latency hiding (16 waves/CU).
// Blocks 0..511: (b,c). Phase A: 8 waves compute mu/rstd for the 64 rows
//   (wave w -> rows e=8w..8w+7, e=(j,r)). Phase B: each thread owns ONE d
//   column, walks 16 base rows x 4 phases with a 2-deep 16-load pipeline.
//   E(s+1024j,k) = E(s,k) * (-i)^{jk}.
// Blocks 512..767: transpose conv_w (O,I,3) -> wTf[t][d][o].
// ---------------------------------------------------------------------------
__global__ __launch_bounds__(512) void k_project(
    const float* __restrict__ x, const float* __restrict__ gamma,
    const float* __restrict__ beta, const float* __restrict__ cw,
    float* __restrict__ wTf, float* __restrict__ partials) {
  int blk = blockIdx.x;
  int tid = threadIdx.x;

  if (blk >= 512) {  // transpose path: 256 blocks x 512 thr x 6 elems
    int base0 = (blk - 512) * 3072;
#pragma unroll
    for (int u = 0; u < 6; ++u) {
      int idx = base0 + (u << 9) + tid;
      int o = idx & 511;
      int d = (idx >> 9) & 511;
      int t = idx >> 18;
      wTf[idx] = cw[o * 1536 + d * 3 + t];
    }
    return;
  }

  int b = blk >> 6;
  int c = blk & 63;
  int s_base = c << 4;  // base rows s_base..s_base+15 (0..1023)
  int d = tid;          // one d column per thread

  __shared__ __attribute__((aligned(16))) float2 s_tw[16][MODES];  // 2 KB
  __shared__ float2 s_mv[64];                                      // 512 B

  // twiddles for the 16 base rows
  if (tid < 256) {
    int r = tid >> 4, k = tid & 15;
    int m = ((s_base + r) * k) & (Sn - 1);
    float sn, cn;
    __sincosf((float)m * ANGF, &sn, &cn);
    s_tw[r][k] = make_float2(cn, sn);
  }

  // Phase A: LN stats. Wave w handles e = 8w..8w+7; e=(j,r): j=e>>4, r=e&15.
  {
    int w = tid >> 6, lane = tid & 63;
#pragma unroll
    for (int eg = 0; eg < 8; eg += 4) {
      float4 v[8];
#pragma unroll
      for (int q = 0; q < 4; ++q) {
        int e = w * 8 + eg + q;
        int row = ((e >> 4) << 10) + s_base + (e & 15);
        const float4* px =
            (const float4*)(x + ((((size_t)(b << 12)) + row) << 9));
        v[2 * q] = px[lane * 2];
        v[2 * q + 1] = px[lane * 2 + 1];
      }
#pragma unroll
      for (int q = 0; q < 4; ++q) {
        float4 v0 = v[2 * q], v1 = v[2 * q + 1];
        float ps = v0.x + v0.y + v0.z + v0.w + v1.x + v1.y + v1.z + v1.w;
        float pq = v0.x * v0.x + v0.y * v0.y + v0.z * v0.z + v0.w * v0.w +
                   v1.x * v1.x + v1.y * v1.y + v1.z * v1.z + v1.w * v1.w;
#pragma unroll
        for (int off = 32; off > 0; off >>= 1) {
          ps += __shfl_down(ps, off);
          pq += __shfl_down(pq, off);
        }
        if (lane == 0) {
          float mu = ps * (1.0f / Dn);
          float var = pq * (1.0f / Dn) - mu * mu;
          s_mv[w * 8 + eg + q] = make_float2(mu, rsqrtf(var + 1e-5f));
        }
      }
    }
  }
  __syncthreads();

  float g = gamma[d], be = beta[d];
  float accRe[MODES], accIm[MODES];
#pragma unroll
  for (int k = 0; k < MODES; k++) { accRe[k] = 0.f; accIm[k] = 0.f; }

  const float* xb = x + ((((size_t)(b << 12)) + s_base) << 9) + d;

  float qA[16], qB[16];
#define LOADQ(Q, RG)                                                      \
  {                                                                       \
    _Pragma("unroll") for (int j = 0; j < 4; ++j) {                       \
      _Pragma("unroll") for (int rr = 0; rr < 4; ++rr) {                  \
        Q[j * 4 + rr] = xb[(size_t)((j << 10) + (RG)*4 + rr) << 9];       \
      }                                                                   \
    }                                                                     \
  }
#define PROCQ(Q, RG)                                                      \
  {                                                                       \
    _Pragma("unroll") for (int rr = 0; rr < 4; ++rr) {                    \
      int r = (RG)*4 + rr;                                                \
      float xn[4];                                                        \
      _Pragma("unroll") for (int j = 0; j < 4; ++j) {                     \
        float2 mv = s_mv[(j << 4) + r];                                   \
        xn[j] = (Q[j * 4 + rr] - mv.x) * (mv.y * g) + be;                 \
      }                                                                   \
      float t02p = xn[0] + xn[2], t02m = xn[0] - xn[2];                   \
      float t13p = xn[1] + xn[3], t13m = xn[1] - xn[3];                   \
      float u0 = t02p + t13p, u1 = t02p - t13p;                           \
      const float4* twr = (const float4*)&s_tw[r][0];                     \
      _Pragma("unroll") for (int kk = 0; kk < 8; ++kk) {                  \
        float4 t2 = twr[kk];                                              \
        const int k0 = 2 * kk, k1 = 2 * kk + 1;                           \
        float u = ((k0 & 3) == 0) ? u0 : u1;                              \
        accRe[k0] += u * t2.x;                                            \
        accIm[k0] -= u * t2.y;                                            \
        if ((k1 & 3) == 1) { /* F = t02m - i*t13m; acc += (c - i s)F */   \
          accRe[k1] += t2.z * t02m - t2.w * t13m;                         \
          accIm[k1] -= t2.z * t13m + t2.w * t02m;                         \
        } else { /* k%4==3: F = t02m + i*t13m */                          \
          accRe[k1] += t2.z * t02m + t2.w * t13m;                         \
          accIm[k1] += t2.z * t13m - t2.w * t02m;                         \
        }                                                                 \
      }                                                                   \
    }                                                                     \
  }

  LOADQ(qA, 0);
  LOADQ(qB, 1);
  PROCQ(qA, 0);
  LOADQ(qA, 2);
  PROCQ(qB, 1);
  LOADQ(qB, 3);
  PROCQ(qA, 2);
  PROCQ(qB, 3);
#undef LOADQ
#undef PROCQ

  size_t base = ((size_t)(b * 64 + c)) * MODES;
  float2* P2 = (float2*)partials;
#pragma unroll
  for (int k = 0; k < MODES; k++)
    P2[(base + k) * Dn + d] = make_float2(accRe[k], accIm[k]);
}

// ---------------------------------------------------------------------------
// K2: reduce partials over 64 chunks, apply spectral weight, ortho norms.
// ---------------------------------------------------------------------------
__global__ __launch_bounds__(256) void k_reduce_modes(
    const float* __restrict__ partials, const float* __restrict__ wr,
    const float* __restrict__ wi, float* __restrict__ Y) {
  int idx = blockIdx.x * 256 + threadIdx.x;  // 65536
  int d = idx & 511;
  int k = (idx >> 9) & 15;
  int b = idx >> 13;
  const float2* P = (const float2*)partials;
  float re = 0.f, im = 0.f;
#pragma unroll 8
  for (int c = 0; c < 64; c++) {
    float2 p = P[(((size_t)(b * 64 + c)) * MODES + k) * Dn + d];
    re += p.x;
    im += p.y;
  }
  float wrv = wr[d * MODES + k];
  float wiv = wi[d * MODES + k];
  float yre = re * wrv - im * wiv;
  float yim = re * wiv + im * wrv;
  float scale = (k == 0) ? (1.0f / 4096.0f) : (2.0f / 4096.0f);
  ((float2*)Y)[((size_t)b * MODES + k) * Dn + d] =
      make_float2(yre * scale, yim * scale);
}

// ---------------------------------------------------------------------------
// KZ: Z[b,t][k][o] = sum_d Yhat[b,k,d] * w[o,d,t]  (FULLY summed over d).
// Grid 768 = b(8) x t(3) x och(32); 256 thr = 16 k x 16 o (one pair each).
// LDS Y-tile [16][129] (padded: unpadded gives 4-way bank alias since all
// k-groups land on bank 2*dd). Whole wave reads ONE 64B wTf line per d-step.
// ---------------------------------------------------------------------------
__global__ __launch_bounds__(256) void k_build_z(
    const float* __restrict__ Y, const float* __restrict__ wTf,
    float* __restrict__ Z) {
  int blk = blockIdx.x;
  int b = blk / 96;
  int rem = blk % 96;
  int t = rem >> 5;
  int och = rem & 31;
  int tid = threadIdx.x;
  int k = tid >> 4, oi = tid & 15;
  int o = (och << 4) + oi;

  __shared__ float2 Ys[MODES][129];  // ~16.1 KB
  const float2* Y2 = (const float2*)Y;

  float zc = 0.f, zs = 0.f;
  for (int dch = 0; dch < 4; ++dch) {
    int d0 = dch << 7;
#pragma unroll
    for (int i = 0; i < 8; i++) {
      int e = tid + (i << 8);  // 2048
      int kk = e >> 7, dd = e & 127;
      Ys[kk][dd] = Y2[(((size_t)(b * MODES + kk)) << 9) + d0 + dd];
    }
    __syncthreads();

    const float* wp = wTf + (((size_t)(t * Dn + d0)) << 9) + o;
#pragma unroll 8
    for (int dd = 0; dd < 128; ++dd) {
      float wv = wp[(size_t)dd << 9];
      float2 y = Ys[k][dd];
      zc += y.x * wv;
      zs += y.y * wv;
    }
    __syncthreads();
  }

  ((float2*)Z)[(((size_t)((b * 3 + t) * MODES + k)) << 9) + o] =
      make_float2(zc, zs);
}

// ---------------------------------------------------------------------------
// K5: fused G-build + apply.
// Prologue (registers, per thread's float2 of o):
//   G_k = Yhat_k + e^{-i phi} Z0 + Z1 + e^{+i phi} Z2   (phi = 2pi k/S)
//   V0 = sum_k Re(e^{-i phi} Z0), V1 = sum_k Re(Z2)
// Main loop: out[b,s,o] = x + conv_b + sum_k Re(G_k e^{i 2pi s k/S}),
// minus V0 at s=0 / V1 at s=S-1. Radix-4 over phases j*1024 via i^{jk}.
// Grid 1024 = b(8) x rt(128); 8 base rows per block.
// ---------------------------------------------------------------------------
__global__ __launch_bounds__(256) void k_apply(
    const float* __restrict__ x, const float* __restrict__ Y,
    const float* __restrict__ Z, const float* __restrict__ conv_b,
    float* __restrict__ out) {
  int b = blockIdx.x >> 7;
  int rt = blockIdx.x & 127;
  int r0 = rt << 3;  // base rows r0..r0+7 (0..1023)
  int tid = threadIdx.x;
  int o0 = tid << 1;

  __shared__ __attribute__((aligned(16))) float2 s_tw[8][MODES];  // 1 KB
  if (tid < 128) {
    int rr = tid >> 4, k = tid & 15;
    int m = ((r0 + rr) * k) & (Sn - 1);
    float sn, cn;
    __sincosf((float)m * ANGF, &sn, &cn);
    s_tw[rr][k] = make_float2(cn, sn);
  }

  // ---- prologue: build Gc/Gs and V0/V1 in registers ----
  float2 Gc[MODES], Gs[MODES];
  float v0x = 0.f, v0y = 0.f, v1x = 0.f, v1y = 0.f;
  {
    const float4* Y4 = (const float4*)(Y + (((size_t)b * MODES) << 10));
    const float4* Z4 = (const float4*)(Z + (((size_t)b * 3 * MODES) << 10));
#pragma unroll
    for (int k = 0; k < MODES; k++) {
      float sf, cf;
      __sincosf((float)k * ANGF, &sf, &cf);
      float4 z0 = Z4[((0 * MODES + k) << 8) + tid];  // (c,s) for o0, o0+1
      float4 z1 = Z4[((1 * MODES + k) << 8) + tid];
      float4 z2 = Z4[((2 * MODES + k) << 8) + tid];
      float4 y = Y4[(k << 8) + tid];
      // channel o0
      float r0x = cf * z0.x + sf * z0.y;
      float i0x = cf * z0.y - sf * z0.x;
      float r2x = cf * z2.x - sf * z2.y;
      float i2x = cf * z2.y + sf * z2.x;
      Gc[k].x = y.x + r0x + z1.x + r2x;
      Gs[k].x = y.y + i0x + z1.y + i2x;
      // channel o0+1
      float r0y = cf * z0.z + sf * z0.w;
      float i0y = cf * z0.w - sf * z0.z;
      float r2y = cf * z2.z - sf * z2.w;
      float i2y = cf * z2.w + sf * z2.z;
      Gc[k].y = y.z + r0y + z1.z + r2y;
      Gs[k].y = y.w + i0y + z1.w + i2y;
      v0x += r0x; v0y += r0y;
      v1x += z2.x; v1y += z2.z;
    }
  }
  float2 cb2 = *(const float2*)&conv_b[o0];
  __syncthreads();

  const float* xb = x + (((size_t)b << 12) << 9) + o0;
  float* ob = out + (((size_t)b << 12) << 9) + o0;

  float2 cur[4], nxt[4];
#pragma unroll
  for (int j = 0; j < 4; ++j)
    cur[j] = *(const float2*)(xb + ((size_t)((j << 10) + r0) << 9));

#pragma unroll 2
  for (int rr = 0; rr < 8; ++rr) {
    if (rr < 7) {
#pragma unroll
      for (int j = 0; j < 4; ++j)
        nxt[j] = *(const float2*)(xb + ((size_t)((j << 10) + r0 + rr + 1) << 9));
    }
    float2 a0 = make_float2(0.f, 0.f), a1 = a0, a2 = a0, a3 = a0;
    const float4* twr = (const float4*)&s_tw[rr][0];
#pragma unroll
    for (int kk = 0; kk < 8; ++kk) {
      float4 t2 = twr[kk];
#define APPLY_K(kidx, cc, ss)                                          \
  {                                                                    \
    float2 Pre = make_float2(cc * Gc[kidx].x - ss * Gs[kidx].x,        \
                             cc * Gc[kidx].y - ss * Gs[kidx].y);       \
    float2 Pim = make_float2(cc * Gs[kidx].x + ss * Gc[kidx].x,        \
                             cc * Gs[kidx].y + ss * Gc[kidx].y);       \
    a0.x += Pre.x; a0.y += Pre.y;                                      \
    if (((kidx) & 3) == 0) {                                           \
      a1.x += Pre.x; a1.y += Pre.y;                                    \
      a2.x += Pre.x; a2.y += Pre.y;                                    \
      a3.x += Pre.x; a3.y += Pre.y;                                    \
    } else if (((kidx) & 3) == 1) {                                    \
      a1.x -= Pim.x; a1.y -= Pim.y;                                    \
      a2.x -= Pre.x; a2.y -= Pre.y;                                    \
      a3.x += Pim.x; a3.y += Pim.y;                                    \
    } else if (((kidx) & 3) == 2) {                                    \
      a1.x -= Pre.x; a1.y -= Pre.y;                                    \
      a2.x += Pre.x; a2.y += Pre.y;                                    \
      a3.x -= Pre.x; a3.y -= Pre.y;                                    \
    } else {                                                           \
      a1.x += Pim.x; a1.y += Pim.y;                                    \
      a2.x -= Pre.x; a2.y -= Pre.y;                                    \
      a3.x -= Pim.x; a3.y -= Pim.y;                                    \
    }                                                                  \
  }
      APPLY_K(2 * kk, t2.x, t2.y);
      APPLY_K(2 * kk + 1, t2.z, t2.w);
#undef APPLY_K
    }
    int s_r = r0 + rr;
#pragma unroll
    for (int j = 0; j < 4; ++j) {
      float2 aj = (j == 0) ? a0 : (j == 1) ? a1 : (j == 2) ? a2 : a3;
      int s = s_r + (j << 10);
      float2 o2 = make_float2(cur[j].x + cb2.x + aj.x,
                              cur[j].y + cb2.y + aj.y);
      if (s == 0) { o2.x -= v0x; o2.y -= v0y; }
      if (s == Sn - 1) { o2.x -= v1x; o2.y -= v1y; }
      *(float2*)(ob + ((size_t)s << 9)) = o2;
    }
#pragma unroll
    for (int j = 0; j < 4; ++j) cur[j] = nxt[j];
  }
}

// ---------------------------------------------------------------------------
extern "C" void kernel_launch(void* const* d_in, const int* in_sizes, int n_in,
                              void* d_out, int out_size, void* d_ws,
                              size_t ws_size, hipStream_t stream) {
  const float* x = (const float*)d_in[0];
  const float* gamma = (const float*)d_in[1];
  const float* beta = (const float*)d_in[2];
  const float* wr = (const float*)d_in[3];
  const float* wi = (const float*)d_in[4];
  const float* conv_w = (const float*)d_in[5];
  const float* conv_b = (const float*)d_in[6];
  float* out = (float*)d_out;

  float* ws = (float*)d_ws;
  float* partials = ws + PART_OFF;
  float* Y = ws + Y_OFF;
  float* wTf = ws + WTF_OFF;
  float* Z = ws + Z_OFF;

  hipLaunchKernelGGL(k_project, dim3(768), dim3(512), 0, stream, x, gamma,
                     beta, conv_w, wTf, partials);
  hipLaunchKernelGGL(k_reduce_modes, dim3(256), dim3(256), 0, stream, partials,
                     wr, wi, Y);
  hipLaunchKernelGGL(k_build_z, dim3(768), dim3(256), 0, stream, Y, wTf, Z);
  hipLaunchKernelGGL(k_apply, dim3(1024), dim3(256), 0, stream, x, Y, Z,
                     conv_b, out);
}

// Round 5
// 206.612 us; speedup vs baseline: 1.3054x; 1.3054x over previous
//
#include <hip/hip_runtime.h>
#include <hip/hip_bf16.h>
#include <math.h>

// Problem constants
#define Bn 8
#define Sn 4096
#define Dn 512
#define MODES 16
#define ANGF 0.0015339807878856412f  // 2*pi/4096

// ws layout (floats):
#define PART_OFF 0               //  8,388,608  fp32 [B*64][16][512] float2
#define Y_OFF 8388608            //  + 131,072  fp32 [B][16][512] float2
#define WTF_OFF 8519680          //  + 786,432  fp32 [3][512 d][512 o]
#define Z_OFF 9306112            //  + 393,216  fp32 [B][3 t][16][512] float2
#define STATS_OFF 9699328        //  +  65,536  fp32 [B*4096] float2 (mu, rstd)

// ---------------------------------------------------------------------------
// K1a: per-row LayerNorm stats (blocks 0..1023, 32 rows each; wave = 8 rows)
//      + conv_w transpose (blocks 1024..1279): wTf[t][d][o] = cw[o,d,t].
// Both memory-bound, independent work fused into one dispatch.
// ---------------------------------------------------------------------------
__global__ __launch_bounds__(256) void k_stats(const float* __restrict__ x,
                                               const float* __restrict__ cw,
                                               float* __restrict__ wTf,
                                               float2* __restrict__ stats) {
  int blk = blockIdx.x;
  int tid = threadIdx.x;

  if (blk >= 1024) {  // transpose path: 256 blocks x 256 thr x 12 elems
    int base0 = (blk - 1024) * 3072;
#pragma unroll
    for (int u = 0; u < 12; ++u) {
      int idx = base0 + (u << 8) + tid;
      int o = idx & 511;
      int d = (idx >> 9) & 511;
      int t = idx >> 18;
      wTf[idx] = cw[o * 1536 + d * 3 + t];
    }
    return;
  }

  int wave = tid >> 6, lane = tid & 63;
  int row0 = blk * 32 + wave * 8;
  for (int j = 0; j < 8; ++j) {
    int row = row0 + j;
    const float4* px = (const float4*)(x + ((size_t)row << 9));
    float4 v0 = px[lane * 2];
    float4 v1 = px[lane * 2 + 1];
    float ps = v0.x + v0.y + v0.z + v0.w + v1.x + v1.y + v1.z + v1.w;
    float pq = v0.x * v0.x + v0.y * v0.y + v0.z * v0.z + v0.w * v0.w +
               v1.x * v1.x + v1.y * v1.y + v1.z * v1.z + v1.w * v1.w;
#pragma unroll
    for (int off = 32; off > 0; off >>= 1) {
      ps += __shfl_down(ps, off);
      pq += __shfl_down(pq, off);
    }
    if (lane == 0) {
      float mu = ps * (1.0f / Dn);
      float var = pq * (1.0f / Dn) - mu * mu;
      stats[row] = make_float2(mu, rsqrtf(var + 1e-5f));
    }
  }
}

// ---------------------------------------------------------------------------
// K1b: radix-4 16-mode DFT projection of LayerNorm output (round-1 version).
// E(s+1024j, k) = E(s,k) * (-i)^{jk}, so rows {s, s+1024, s+2048, s+3072}
// share one twiddle. Chunk c covers base rows c*16..c*16+15 across all 4
// phases (64 rows total). Grid 512 = b(8) x c(64); 256 thr, each owns a
// float2 of d.
// ---------------------------------------------------------------------------
__global__ __launch_bounds__(256) void k_project(
    const float* __restrict__ x, const float* __restrict__ gamma,
    const float* __restrict__ beta, const float2* __restrict__ stats,
    float* __restrict__ partials) {
  int blk = blockIdx.x;
  int b = blk >> 6;
  int c = blk & 63;
  int tid = threadIdx.x;
  int d0 = tid << 1;
  int s_base = c << 4;  // base rows s_base..s_base+15 (0..1023)

  __shared__ __attribute__((aligned(16))) float2 s_tw[16][MODES];  // 2 KB
  __shared__ float2 s_mv[64];                                      // 512 B
  {
    int r = tid >> 4, k = tid & 15;
    int m = ((s_base + r) * k) & (Sn - 1);
    float sn, cn;
    __sincosf((float)m * ANGF, &sn, &cn);
    s_tw[r][k] = make_float2(cn, sn);
    if (tid < 64) {
      // tid = j*16 + r  ->  row = j*1024 + s_base + r
      s_mv[tid] = stats[(b << 12) + ((tid >> 4) << 10) + s_base + (tid & 15)];
    }
  }
  __syncthreads();

  float2 g = *(const float2*)(gamma + d0);
  float2 be = *(const float2*)(beta + d0);

  float2 accRe[MODES], accIm[MODES];
#pragma unroll
  for (int k = 0; k < MODES; k++) {
    accRe[k] = make_float2(0.f, 0.f);
    accIm[k] = make_float2(0.f, 0.f);
  }

  const float* xb = x + (((size_t)b << 12) << 9) + d0;
  float2 cur[4], nxt[4];
#pragma unroll
  for (int j = 0; j < 4; ++j)
    cur[j] = *(const float2*)(xb + ((size_t)((j << 10) + s_base) << 9));

#pragma unroll 2
  for (int r = 0; r < 16; ++r) {
    if (r < 15) {
#pragma unroll
      for (int j = 0; j < 4; ++j)
        nxt[j] =
            *(const float2*)(xb + ((size_t)((j << 10) + s_base + r + 1) << 9));
    }
    // LayerNorm the 4 phase values
    float2 xn[4];
#pragma unroll
    for (int j = 0; j < 4; ++j) {
      float2 mv = s_mv[(j << 4) + r];
      float ax = mv.y * g.x, ay = mv.y * g.y;
      xn[j] = make_float2((cur[j].x - mv.x) * ax + be.x,
                          (cur[j].y - mv.x) * ay + be.y);
    }
    // radix-4 butterfly (real inputs)
    float2 t02p = make_float2(xn[0].x + xn[2].x, xn[0].y + xn[2].y);
    float2 t02m = make_float2(xn[0].x - xn[2].x, xn[0].y - xn[2].y);
    float2 t13p = make_float2(xn[1].x + xn[3].x, xn[1].y + xn[3].y);
    float2 t13m = make_float2(xn[1].x - xn[3].x, xn[1].y - xn[3].y);
    float2 u0 = make_float2(t02p.x + t13p.x, t02p.y + t13p.y);  // k%4==0
    float2 u1 = make_float2(t02p.x - t13p.x, t02p.y - t13p.y);  // k%4==2

    const float4* twr = (const float4*)&s_tw[r][0];
#pragma unroll
    for (int kk = 0; kk < 8; ++kk) {
      float4 t2 = twr[kk];  // (cos,sin) of modes 2kk and 2kk+1
      const int k0 = 2 * kk, k1 = 2 * kk + 1;
      {  // even mode: real combined input
        float2 u = ((k0 & 3) == 0) ? u0 : u1;
        accRe[k0].x += u.x * t2.x;
        accRe[k0].y += u.y * t2.x;
        accIm[k0].x -= u.x * t2.y;
        accIm[k0].y -= u.y * t2.y;
      }
      if ((k1 & 3) == 1) {  // F = t02m - i*t13m ; acc += (c - i s)*F
        accRe[k1].x += t2.z * t02m.x - t2.w * t13m.x;
        accRe[k1].y += t2.z * t02m.y - t2.w * t13m.y;
        accIm[k1].x -= t2.z * t13m.x + t2.w * t02m.x;
        accIm[k1].y -= t2.z * t13m.y + t2.w * t02m.y;
      } else {  // k%4==3: F = t02m + i*t13m
        accRe[k1].x += t2.z * t02m.x + t2.w * t13m.x;
        accRe[k1].y += t2.z * t02m.y + t2.w * t13m.y;
        accIm[k1].x += t2.z * t13m.x - t2.w * t02m.x;
        accIm[k1].y += t2.z * t13m.y - t2.w * t02m.y;
      }
    }
#pragma unroll
    for (int j = 0; j < 4; ++j) cur[j] = nxt[j];
  }

  size_t base = ((size_t)(b * 64 + c)) * MODES;
  float4* P4 = (float4*)partials;
#pragma unroll
  for (int k = 0; k < MODES; k++)
    P4[(base + k) * 256 + tid] =
        make_float4(accRe[k].x, accIm[k].x, accRe[k].y, accIm[k].y);
}

// ---------------------------------------------------------------------------
// K2: reduce partials over 64 chunks, apply spectral weight, ortho norms.
// ---------------------------------------------------------------------------
__global__ __launch_bounds__(256) void k_reduce_modes(
    const float* __restrict__ partials, const float* __restrict__ wr,
    const float* __restrict__ wi, float* __restrict__ Y) {
  int idx = blockIdx.x * 256 + threadIdx.x;  // 65536
  int d = idx & 511;
  int k = (idx >> 9) & 15;
  int b = idx >> 13;
  const float2* P = (const float2*)partials;
  float re = 0.f, im = 0.f;
#pragma unroll 8
  for (int c = 0; c < 64; c++) {
    float2 p = P[(((size_t)(b * 64 + c)) * MODES + k) * Dn + d];
    re += p.x;
    im += p.y;
  }
  float wrv = wr[d * MODES + k];
  float wiv = wi[d * MODES + k];
  float yre = re * wrv - im * wiv;
  float yim = re * wiv + im * wrv;
  float scale = (k == 0) ? (1.0f / 4096.0f) : (2.0f / 4096.0f);
  ((float2*)Y)[((size_t)b * MODES + k) * Dn + d] =
      make_float2(yre * scale, yim * scale);
}

// ---------------------------------------------------------------------------
// KZ: Z[b,t][k][o] = sum_d Yhat[b,k,d] * w[o,d,t]  (FULLY summed over d).
// Grid 768 = b(8) x t(3) x och(32); 256 thr = 16 k x 16 o (one pair each).
// LDS Y-tile [16][129] (padded). Whole wave reads one 64B wTf line per step.
// ---------------------------------------------------------------------------
__global__ __launch_bounds__(256) void k_build_z(
    const float* __restrict__ Y, const float* __restrict__ wTf,
    float* __restrict__ Z) {
  int blk = blockIdx.x;
  int b = blk / 96;
  int rem = blk % 96;
  int t = rem >> 5;
  int och = rem & 31;
  int tid = threadIdx.x;
  int k = tid >> 4, oi = tid & 15;
  int o = (och << 4) + oi;

  __shared__ float2 Ys[MODES][129];  // ~16.1 KB
  const float2* Y2 = (const float2*)Y;

  float zc = 0.f, zs = 0.f;
  for (int dch = 0; dch < 4; ++dch) {
    int d0 = dch << 7;
#pragma unroll
    for (int i = 0; i < 8; i++) {
      int e = tid + (i << 8);  // 2048
      int kk = e >> 7, dd = e & 127;
      Ys[kk][dd] = Y2[(((size_t)(b * MODES + kk)) << 9) + d0 + dd];
    }
    __syncthreads();

    const float* wp = wTf + (((size_t)(t * Dn + d0)) << 9) + o;
#pragma unroll 8
    for (int dd = 0; dd < 128; ++dd) {
      float wv = wp[(size_t)dd << 9];
      float2 y = Ys[k][dd];
      zc += y.x * wv;
      zs += y.y * wv;
    }
    __syncthreads();
  }

  ((float2*)Z)[(((size_t)((b * 3 + t) * MODES + k)) << 9) + o] =
      make_float2(zc, zs);
}

// ---------------------------------------------------------------------------
// K5: fused G-build + apply.
// Prologue (registers, per thread's float2 of o):
//   G_k = Yhat_k + e^{-i phi} Z0 + Z1 + e^{+i phi} Z2   (phi = 2pi k/S)
//   V0 = sum_k Re(e^{-i phi} Z0), V1 = sum_k Re(Z2)
// Main loop: out[b,s,o] = x + conv_b + sum_k Re(G_k e^{i 2pi s k/S}),
// minus V0 at s=0 / V1 at s=S-1. Radix-4 over phases j*1024 via i^{jk}.
// Grid 1024 = b(8) x rt(128); 8 base rows per block.
// ---------------------------------------------------------------------------
__global__ __launch_bounds__(256) void k_apply(
    const float* __restrict__ x, const float* __restrict__ Y,
    const float* __restrict__ Z, const float* __restrict__ conv_b,
    float* __restrict__ out) {
  int b = blockIdx.x >> 7;
  int rt = blockIdx.x & 127;
  int r0 = rt << 3;  // base rows r0..r0+7 (0..1023)
  int tid = threadIdx.x;
  int o0 = tid << 1;

  __shared__ __attribute__((aligned(16))) float2 s_tw[8][MODES];  // 1 KB
  if (tid < 128) {
    int rr = tid >> 4, k = tid & 15;
    int m = ((r0 + rr) * k) & (Sn - 1);
    float sn, cn;
    __sincosf((float)m * ANGF, &sn, &cn);
    s_tw[rr][k] = make_float2(cn, sn);
  }

  // ---- prologue: build Gc/Gs and V0/V1 in registers ----
  float2 Gc[MODES], Gs[MODES];
  float v0x = 0.f, v0y = 0.f, v1x = 0.f, v1y = 0.f;
  {
    const float4* Y4 = (const float4*)(Y + (((size_t)b * MODES) << 10));
    const float4* Z4 = (const float4*)(Z + (((size_t)b * 3 * MODES) << 10));
#pragma unroll
    for (int k = 0; k < MODES; k++) {
      float sf, cf;
      __sincosf((float)k * ANGF, &sf, &cf);
      float4 z0 = Z4[((0 * MODES + k) << 8) + tid];  // (c,s) for o0, o0+1
      float4 z1 = Z4[((1 * MODES + k) << 8) + tid];
      float4 z2 = Z4[((2 * MODES + k) << 8) + tid];
      float4 y = Y4[(k << 8) + tid];
      // channel o0
      float r0x = cf * z0.x + sf * z0.y;
      float i0x = cf * z0.y - sf * z0.x;
      float r2x = cf * z2.x - sf * z2.y;
      float i2x = cf * z2.y + sf * z2.x;
      Gc[k].x = y.x + r0x + z1.x + r2x;
      Gs[k].x = y.y + i0x + z1.y + i2x;
      // channel o0+1
      float r0y = cf * z0.z + sf * z0.w;
      float i0y = cf * z0.w - sf * z0.z;
      float r2y = cf * z2.z - sf * z2.w;
      float i2y = cf * z2.w + sf * z2.z;
      Gc[k].y = y.z + r0y + z1.z + r2y;
      Gs[k].y = y.w + i0y + z1.w + i2y;
      v0x += r0x; v0y += r0y;
      v1x += z2.x; v1y += z2.z;
    }
  }
  float2 cb2 = *(const float2*)&conv_b[o0];
  __syncthreads();

  const float* xb = x + (((size_t)b << 12) << 9) + o0;
  float* ob = out + (((size_t)b << 12) << 9) + o0;

  float2 cur[4], nxt[4];
#pragma unroll
  for (int j = 0; j < 4; ++j)
    cur[j] = *(const float2*)(xb + ((size_t)((j << 10) + r0) << 9));

#pragma unroll 2
  for (int rr = 0; rr < 8; ++rr) {
    if (rr < 7) {
#pragma unroll
      for (int j = 0; j < 4; ++j)
        nxt[j] = *(const float2*)(xb + ((size_t)((j << 10) + r0 + rr + 1) << 9));
    }
    float2 a0 = make_float2(0.f, 0.f), a1 = a0, a2 = a0, a3 = a0;
    const float4* twr = (const float4*)&s_tw[rr][0];
#pragma unroll
    for (int kk = 0; kk < 8; ++kk) {
      float4 t2 = twr[kk];
#define APPLY_K(kidx, cc, ss)                                          \
  {                                                                    \
    float2 Pre = make_float2(cc * Gc[kidx].x - ss * Gs[kidx].x,        \
                             cc * Gc[kidx].y - ss * Gs[kidx].y);       \
    float2 Pim = make_float2(cc * Gs[kidx].x + ss * Gc[kidx].x,        \
                             cc * Gs[kidx].y + ss * Gc[kidx].y);       \
    a0.x += Pre.x; a0.y += Pre.y;                                      \
    if (((kidx) & 3) == 0) {                                           \
      a1.x += Pre.x; a1.y += Pre.y;                                    \
      a2.x += Pre.x; a2.y += Pre.y;                                    \
      a3.x += Pre.x; a3.y += Pre.y;                                    \
    } else if (((kidx) & 3) == 1) {                                    \
      a1.x -= Pim.x; a1.y -= Pim.y;                                    \
      a2.x -= Pre.x; a2.y -= Pre.y;                                    \
      a3.x += Pim.x; a3.y += Pim.y;                                    \
    } else if (((kidx) & 3) == 2) {                                    \
      a1.x -= Pre.x; a1.y -= Pre.y;                                    \
      a2.x += Pre.x; a2.y += Pre.y;                                    \
      a3.x -= Pre.x; a3.y -= Pre.y;                                    \
    } else {                                                           \
      a1.x += Pim.x; a1.y += Pim.y;                                    \
      a2.x -= Pre.x; a2.y -= Pre.y;                                    \
      a3.x -= Pim.x; a3.y -= Pim.y;                                    \
    }                                                                  \
  }
      APPLY_K(2 * kk, t2.x, t2.y);
      APPLY_K(2 * kk + 1, t2.z, t2.w);
#undef APPLY_K
    }
    int s_r = r0 + rr;
#pragma unroll
    for (int j = 0; j < 4; ++j) {
      float2 aj = (j == 0) ? a0 : (j == 1) ? a1 : (j == 2) ? a2 : a3;
      int s = s_r + (j << 10);
      float2 o2 = make_float2(cur[j].x + cb2.x + aj.x,
                              cur[j].y + cb2.y + aj.y);
      if (s == 0) { o2.x -= v0x; o2.y -= v0y; }
      if (s == Sn - 1) { o2.x -= v1x; o2.y -= v1y; }
      *(float2*)(ob + ((size_t)s << 9)) = o2;
    }
#pragma unroll
    for (int j = 0; j < 4; ++j) cur[j] = nxt[j];
  }
}

// ---------------------------------------------------------------------------
extern "C" void kernel_launch(void* const* d_in, const int* in_sizes, int n_in,
                              void* d_out, int out_size, void* d_ws,
                              size_t ws_size, hipStream_t stream) {
  const float* x = (const float*)d_in[0];
  const float* gamma = (const float*)d_in[1];
  const float* beta = (const float*)d_in[2];
  const float* wr = (const float*)d_in[3];
  const float* wi = (const float*)d_in[4];
  const float* conv_w = (const float*)d_in[5];
  const float* conv_b = (const float*)d_in[6];
  float* out = (float*)d_out;

  float* ws = (float*)d_ws;
  float* partials = ws + PART_OFF;
  float* Y = ws + Y_OFF;
  float* wTf = ws + WTF_OFF;
  float* Z = ws + Z_OFF;
  float2* stats = (float2*)(ws + STATS_OFF);

  hipLaunchKernelGGL(k_stats, dim3(1280), dim3(256), 0, stream, x, conv_w,
                     wTf, stats);
  hipLaunchKernelGGL(k_project, dim3(512), dim3(256), 0, stream, x, gamma,
                     beta, stats, partials);
  hipLaunchKernelGGL(k_reduce_modes, dim3(256), dim3(256), 0, stream, partials,
                     wr, wi, Y);
  hipLaunchKernelGGL(k_build_z, dim3(768), dim3(256), 0, stream, Y, wTf, Z);
  hipLaunchKernelGGL(k_apply, dim3(1024), dim3(256), 0, stream, x, Y, Z,
                     conv_b, out);
}